// Round 6
// baseline (210.396 us; speedup 1.0000x reference)
//
#include <hip/hip_runtime.h>
#include <math.h>

#define N_POINTS 4000000
#define N_PLANES 64
#define THRESH   0.02f
#define NVALS    (N_PLANES*10)   // 640
#define RBLOCKS  2048            // reduce grid cap (2560 B partial per block)
#define RTHREADS 256             // 4 waves per block
#define UB       8               // points per SGPR batch (double-buffered)

// ---------------------------------------------------------------------------
// Stage 1: plane-per-lane moment reduction, software-pipelined.
// lane = plane id; each wave streams a contiguous point range. Point coords
// are wave-uniform -> scalarized to s_load batches. Two SGPR batches in
// flight: issue loads for batch k+1, then compute batch k.
// ---------------------------------------------------------------------------
__device__ __forceinline__
void load_batch(const float* __restrict__ pts, int b,
                float (&X)[UB], float (&Y)[UB], float (&Z)[UB])
{
#pragma unroll
    for (int u = 0; u < UB; ++u) {
        int ix = b + u;
        ix = (ix < N_POINTS) ? ix : (N_POINTS - 1);   // safe over-read, never accumulated
        X[u] = pts[ix*3+0];
        Y[u] = pts[ix*3+1];
        Z[u] = pts[ix*3+2];
    }
}

__device__ __forceinline__
void comp_batch(const float (&X)[UB], const float (&Y)[UB], const float (&Z)[UB],
                float nx, float ny, float nz, float nd,
                float& cnt, float& sx, float& sy, float& sz,
                float& xx, float& xy, float& xz,
                float& yy, float& yz, float& zz)
{
#pragma unroll
    for (int u = 0; u < UB; ++u) {
        const float t  = fmaf(X[u], nx, fmaf(Y[u], ny, fmaf(Z[u], nz, nd)));
        const float fm = (fabsf(t) < THRESH) ? 1.0f : 0.0f;
        const float tx = fm * X[u], ty = fm * Y[u], tz = fm * Z[u];
        cnt += fm;
        sx += tx; sy += ty; sz += tz;
        xx = fmaf(tx, X[u], xx); xy = fmaf(tx, Y[u], xy); xz = fmaf(tx, Z[u], xz);
        yy = fmaf(ty, Y[u], yy); yz = fmaf(ty, Z[u], yz); zz = fmaf(tz, Z[u], zz);
    }
}

__global__ __launch_bounds__(RTHREADS)
void reduce_kernel(const float* __restrict__ pts,
                   const float* __restrict__ nrm,
                   const float* __restrict__ dst,
                   float* __restrict__ partials, int ppw)
{
    const int lane = threadIdx.x & 63;
    const int wid  = __builtin_amdgcn_readfirstlane((int)(threadIdx.x >> 6));
    const int gwave = blockIdx.x * (RTHREADS/64) + wid;

    const float nx = nrm[lane*3+0];
    const float ny = nrm[lane*3+1];
    const float nz = nrm[lane*3+2];
    const float nd = -dst[lane];

    float cnt=0.f, sx=0.f, sy=0.f, sz=0.f;
    float xx=0.f, xy=0.f, xz=0.f, yy=0.f, yz=0.f, zz=0.f;

    int beg = gwave * ppw; if (beg > N_POINTS) beg = N_POINTS;
    int end = beg + ppw;   if (end > N_POINTS) end = N_POINTS;

    float XA[UB], YA[UB], ZA[UB], XB[UB], YB[UB], ZB[UB];

    int j = beg;
    if (j + UB <= end)
        load_batch(pts, j, XA, YA, ZA);                 // prologue: batch [j, j+8)

    // invariant at loop top: XA/YA/ZA hold [j, j+UB)
    for (; j + 2*UB <= end; j += 2*UB) {
        load_batch(pts, j + UB, XB, YB, ZB);            // issue loads for B
        comp_batch(XA, YA, ZA, nx, ny, nz, nd, cnt, sx, sy, sz, xx, xy, xz, yy, yz, zz);
        load_batch(pts, j + 2*UB, XA, YA, ZA);          // issue loads for next A (clamped)
        comp_batch(XB, YB, ZB, nx, ny, nz, nd, cnt, sx, sy, sz, xx, xy, xz, yy, yz, zz);
    }
    if (j + UB <= end) {                                // XA holds [j, j+8)
        comp_batch(XA, YA, ZA, nx, ny, nz, nd, cnt, sx, sy, sz, xx, xy, xz, yy, yz, zz);
        j += UB;
    }
    for (; j < end; ++j) {                              // scalar tail (<8 points)
        const float x = pts[j*3+0];
        const float y = pts[j*3+1];
        const float z = pts[j*3+2];
        const float t  = fmaf(x, nx, fmaf(y, ny, fmaf(z, nz, nd)));
        const float fm = (fabsf(t) < THRESH) ? 1.0f : 0.0f;
        const float tx = fm * x, ty = fm * y, tz = fm * z;
        cnt += fm;
        sx += tx; sy += ty; sz += tz;
        xx = fmaf(tx, x, xx); xy = fmaf(tx, y, xy); xz = fmaf(tx, z, xz);
        yy = fmaf(ty, y, yy); yz = fmaf(ty, z, yz); zz = fmaf(tz, z, zz);
    }

    // block combine: 4 per-wave rows -> 1 per-block row of 640 f32
    __shared__ float part[RTHREADS/64][NVALS];
    {
        float* r = &part[threadIdx.x >> 6][lane * 10];
        r[0]=cnt; r[1]=sx; r[2]=sy; r[3]=sz;
        r[4]=xx; r[5]=xy; r[6]=xz; r[7]=yy; r[8]=yz; r[9]=zz;
    }
    __syncthreads();
    for (int v = threadIdx.x; v < NVALS; v += RTHREADS) {
        float s = 0.f;
#pragma unroll
        for (int w = 0; w < RTHREADS/64; ++w) s += part[w][v];
        partials[(long long)blockIdx.x * NVALS + v] = s;
    }
}

// ---------------------------------------------------------------------------
// Stage 2 (fused fit): one block per plane. Stream partials, f64-accumulate,
// thread 0 runs the 3x3 Jacobi eigensolve and writes the merged param row:
//   {nx, ny, nz, -d, vld*rx, vld*ry, vld*rz, -vld*rd}
// ---------------------------------------------------------------------------
__global__ __launch_bounds__(256)
void finalize_kernel(const float* __restrict__ partials, int nb,
                     const float* __restrict__ nrm,
                     const float* __restrict__ dst,
                     float* __restrict__ params)
{
    const int p    = blockIdx.x;
    const int lane = threadIdx.x & 63;
    const int wid  = threadIdx.x >> 6;

    double s[10];
#pragma unroll
    for (int q = 0; q < 10; ++q) s[q] = 0.0;

    for (int b = threadIdx.x; b < nb; b += 256) {
        const float* row = partials + (long long)b * NVALS + p * 10;
#pragma unroll
        for (int q = 0; q < 10; ++q) s[q] += (double)row[q];
    }

#pragma unroll
    for (int off = 32; off; off >>= 1)
#pragma unroll
        for (int q = 0; q < 10; ++q) s[q] += __shfl_xor(s[q], off);

    __shared__ double wsum[4][10];
    if (lane == 0) {
#pragma unroll
        for (int q = 0; q < 10; ++q) wsum[wid][q] = s[q];
    }
    __syncthreads();
    if (threadIdx.x != 0) return;

    double a[10];
#pragma unroll
    for (int q = 0; q < 10; ++q)
        a[q] = wsum[0][q] + wsum[1][q] + wsum[2][q] + wsum[3][q];

    const double cnt = a[0];
    const double sx = a[1], sy = a[2], sz = a[3];
    const double den = fmax(cnt, 1.0);
    const double cx = sx / den, cy = sy / den, cz = sz / den;

    double C[3][3];
    C[0][0] = a[4] - 2.0*cx*sx + cnt*cx*cx;
    C[0][1] = a[5] - cx*sy - cy*sx + cnt*cx*cy;
    C[0][2] = a[6] - cx*sz - cz*sx + cnt*cx*cz;
    C[1][1] = a[7] - 2.0*cy*sy + cnt*cy*cy;
    C[1][2] = a[8] - cy*sz - cz*sy + cnt*cy*cz;
    C[2][2] = a[9] - 2.0*cz*sz + cnt*cz*cz;
    C[1][0] = C[0][1]; C[2][0] = C[0][2]; C[2][1] = C[1][2];

    const double valid = (cnt >= 3.0) ? 1.0 : 0.0;
    C[0][0] += (1.0 - valid) * 1.0;
    C[1][1] += (1.0 - valid) * 2.0;
    C[2][2] += (1.0 - valid) * 3.0;

    double V[3][3] = {{1,0,0},{0,1,0},{0,0,1}};
    for (int sweep = 0; sweep < 15; ++sweep) {
#pragma unroll
        for (int k = 0; k < 3; ++k) {
            const int pp = (k == 2) ? 1 : 0;
            const int qq = (k == 0) ? 1 : 2;
            const int rr = 3 - pp - qq;
            const double apq = C[pp][qq];
            if (fabs(apq) < 1e-300) continue;
            const double theta = (C[qq][qq] - C[pp][pp]) / (2.0 * apq);
            const double t = copysign(1.0, theta) / (fabs(theta) + sqrt(theta*theta + 1.0));
            const double c = 1.0 / sqrt(t*t + 1.0);
            const double ss = t * c;
            const double app = C[pp][pp], aqq = C[qq][qq];
            const double arp = C[rr][pp], arq = C[rr][qq];
            C[pp][pp] = app - t * apq;
            C[qq][qq] = aqq + t * apq;
            C[pp][qq] = 0.0; C[qq][pp] = 0.0;
            const double nrp = c*arp - ss*arq;
            const double nrq = ss*arp + c*arq;
            C[rr][pp] = nrp; C[pp][rr] = nrp;
            C[rr][qq] = nrq; C[qq][rr] = nrq;
#pragma unroll
            for (int i = 0; i < 3; ++i) {
                const double vip = V[i][pp], viq = V[i][qq];
                V[i][pp] = c*vip - ss*viq;
                V[i][qq] = ss*vip + c*viq;
            }
        }
    }

    int idx = 0;
    if (C[1][1] < C[idx][idx]) idx = 1;
    if (C[2][2] < C[idx][idx]) idx = 2;
    double rx = V[0][idx], ry = V[1][idx], rz = V[2][idx];
    const double inv = 1.0 / sqrt(rx*rx + ry*ry + rz*rz);
    rx *= inv; ry *= inv; rz *= inv;

    const double nxd = (double)nrm[p*3+0];
    const double nyd = (double)nrm[p*3+1];
    const double nzd = (double)nrm[p*3+2];
    if (rx*nxd + ry*nyd + rz*nzd < 0.0) { rx = -rx; ry = -ry; rz = -rz; }
    const double rd = cx*rx + cy*ry + cz*rz;

    const float vldf = (float)valid;
    params[p*8+0] = nrm[p*3+0];
    params[p*8+1] = nrm[p*3+1];
    params[p*8+2] = nrm[p*3+2];
    params[p*8+3] = -dst[p];
    params[p*8+4] = vldf * (float)rx;
    params[p*8+5] = vldf * (float)ry;
    params[p*8+6] = vldf * (float)rz;
    params[p*8+7] = -(vldf * (float)rd);
}

// ---------------------------------------------------------------------------
// Stage 3: projection, 4 points per thread (ILP + amortized param s_loads).
// Mask expression bit-identical to stage 1. vld folded into rv / rdv.
// ---------------------------------------------------------------------------
#define PPTH 4
#define PQ   (N_POINTS / PPTH)   // 1,000,000

__global__ __launch_bounds__(256)
void project_kernel(const float* __restrict__ pts,
                    const float* __restrict__ params,
                    float* __restrict__ out)
{
    const int tid = blockIdx.x * 256 + threadIdx.x;
    if (tid >= PQ) return;

    float ox[PPTH], oy[PPTH], oz[PPTH];
    float qx[PPTH], qy[PPTH], qz[PPTH];
#pragma unroll
    for (int k = 0; k < PPTH; ++k) {
        const long long i = (long long)tid + (long long)k * PQ;
        ox[k] = pts[i*3+0]; oy[k] = pts[i*3+1]; oz[k] = pts[i*3+2];
        qx[k] = ox[k]; qy[k] = oy[k]; qz[k] = oz[k];
    }

#pragma unroll 2
    for (int p = 0; p < N_PLANES; ++p) {
        const float nx  = params[p*8+0];
        const float ny  = params[p*8+1];
        const float nz  = params[p*8+2];
        const float md  = params[p*8+3];   // -d
        const float rvx = params[p*8+4];   // vld*rx
        const float rvy = params[p*8+5];
        const float rvz = params[p*8+6];
        const float mrd = params[p*8+7];   // -vld*rd

#pragma unroll
        for (int k = 0; k < PPTH; ++k) {
            const float t0 = fmaf(ox[k], nx, fmaf(oy[k], ny, fmaf(oz[k], nz, md)));
            const float t  = fmaf(qx[k], rvx, fmaf(qy[k], rvy, fmaf(qz[k], rvz, mrd)));
            const float tm = (fabsf(t0) < THRESH) ? t : 0.0f;
            qx[k] = fmaf(-tm, rvx, qx[k]);
            qy[k] = fmaf(-tm, rvy, qy[k]);
            qz[k] = fmaf(-tm, rvz, qz[k]);
        }
    }

#pragma unroll
    for (int k = 0; k < PPTH; ++k) {
        const long long i = (long long)tid + (long long)k * PQ;
        out[i*3+0] = qx[k];
        out[i*3+1] = qy[k];
        out[i*3+2] = qz[k];
    }
}

// ---------------------------------------------------------------------------
extern "C" void kernel_launch(void* const* d_in, const int* in_sizes, int n_in,
                              void* d_out, int out_size, void* d_ws, size_t ws_size,
                              hipStream_t stream)
{
    const float* pts = (const float*)d_in[0];
    const float* nrm = (const float*)d_in[1];
    const float* dst = (const float*)d_in[2];
    float* out = (float*)d_out;

    // size the reduce grid to the available scratch (2560 B per block row)
    size_t avail = (ws_size > 8192) ? (ws_size - 8192) : 0;
    int nb = (int)(avail / (NVALS * sizeof(float)));
    if (nb < 1) nb = 1;
    if (nb > RBLOCKS) nb = RBLOCKS;

    float* partials = (float*)d_ws;
    size_t poff = ((size_t)nb * NVALS * sizeof(float) + 255) & ~(size_t)255;
    float* params = (float*)((char*)d_ws + poff);

    const int nwaves = nb * (RTHREADS / 64);
    const int ppw = (int)((N_POINTS + nwaves - 1) / nwaves);

    hipLaunchKernelGGL(reduce_kernel, dim3(nb), dim3(RTHREADS), 0, stream,
                       pts, nrm, dst, partials, ppw);
    hipLaunchKernelGGL(finalize_kernel, dim3(N_PLANES), dim3(256), 0, stream,
                       partials, nb, nrm, dst, params);
    hipLaunchKernelGGL(project_kernel, dim3((PQ + 255) / 256), dim3(256), 0, stream,
                       pts, params, out);
}